// Round 1
// 416.926 us; speedup vs baseline: 1.1946x; 1.1946x over previous
//
#include <hip/hip_runtime.h>
#include <math.h>

#define NN 50000
#define NE 800000
#define MUL 32
#define NPB 4       /* nodes per k_node block */
#define SCANB 49    /* ceil(NN/1024) */

static __device__ __forceinline__ float sigmoidf_(float v) {
    return 1.0f / (1.0f + __expf(-v));
}

#define INV_SQRT_MUL   0.17677669529663687f   /* 1/sqrt(32) */
#define INV_SQRT_NEMB  0.35355339059327373f   /* 1/sqrt(8)  */
#define INV_SQRT_HID   0.35355339059327373f   /* 1/sqrt(8)  */
#define INV3C          0.5773502691896258f    /* 1/sqrt(3)  */
#define INV2C          0.7071067811865476f    /* 1/sqrt(2)  */
#define INV_NEIGH      0.25f                  /* 1/sqrt(16) */
#define INV_SQRT_2MUL  0.125f                 /* 1/sqrt(64) */
#define INV_SQRT_3MUL  0.10206207261596575f   /* 1/sqrt(96) */
#define NSC            0.0625f                /* 1/sqrt(32*8) */

// ---------------------------------------------------------------------------
// K1 (v6): NPB=4 nodes per 256-thread block. Wsc elements loaded ONCE per
// block and applied to all 4 nodes via register-held attrs (at[4][8]) ->
// L2 weight traffic cut ~2.25x vs 2-node version. Histogram of edge_dst is
// fused in (grid covers NE). x layout CHANGED to packed-per-u:
//   x[n*128 + 4*u + 0] = s[u],  x[n*128 + 4*u + 1 + c] = v[u][c]
// so k_gather fetches a lane's whole operand with one dwordx4.
// out layout unchanged: [0..31]=s, [32 + u*3 + c]=v.
// ---------------------------------------------------------------------------
__global__ __launch_bounds__(256) void k_node(
    const float* __restrict__ node_s, const float* __restrict__ node_v,
    const float* __restrict__ attrs,
    const float* __restrict__ W1_s, const float* __restrict__ W1_v,
    const float* __restrict__ Wsc_s, const float* __restrict__ Wsc_v,
    const int* __restrict__ edge_dst, int* __restrict__ counts,
    float* __restrict__ x, float* __restrict__ out)
{
    __shared__ float nd[NPB][136];   // [0..31]=s [32..127]=v [128..135]=attrs
    __shared__ float gs[NPB][1024];  // attr-contracted Wsc_s  [u*32+v]
    __shared__ float gv[NPB][1024];  // attr-contracted Wsc_v
    const int t  = threadIdx.x;
    const int nb = blockIdx.x * NPB;

    // fused dst histogram: grid = 12500*256 = 3.2M threads >= NE
    {
        int g = blockIdx.x * 256 + t;
        if (g < NE) atomicAdd(&counts[edge_dst[g]], 1);
    }

    // stage node data (NPB*128 = 512 elems, 2 per thread)
#pragma unroll
    for (int i = t; i < NPB * 128; i += 256) {
        int nn = i >> 7, j = i & 127;
        nd[nn][j] = (j < 32) ? node_s[(nb + nn) * 32 + j]
                             : node_v[(nb + nn) * 96 + (j - 32)];
    }
    if (t < NPB * 8) nd[t >> 3][128 + (t & 7)] = attrs[(nb + (t >> 3)) * 8 + (t & 7)];
    __syncthreads();

    float at[NPB][8];
#pragma unroll
    for (int nn = 0; nn < NPB; ++nn)
#pragma unroll
        for (int a = 0; a < 8; ++a) at[nn][a] = nd[nn][128 + a];

    // build gs/gv: 1024 (u,v) pairs, 4 per thread; each Wsc element loaded
    // once and used for all NPB nodes
#pragma unroll
    for (int r = 0; r < 4; ++r) {
        const int idx = t + 256 * r;
        const int u = idx >> 5, vch = idx & 31;
        float as[NPB] = {0.f, 0.f, 0.f, 0.f};
        float av[NPB] = {0.f, 0.f, 0.f, 0.f};
#pragma unroll
        for (int a = 0; a < 8; ++a) {
            const float ws = Wsc_s[(u * 8 + a) * 32 + vch];
            const float wv = Wsc_v[(u * 8 + a) * 32 + vch];
#pragma unroll
            for (int nn = 0; nn < NPB; ++nn) {
                as[nn] += at[nn][a] * ws;
                av[nn] += at[nn][a] * wv;
            }
        }
#pragma unroll
        for (int nn = 0; nn < NPB; ++nn) {
            gs[nn][idx] = as[nn];
            gv[nn][idx] = av[nn];
        }
    }
    __syncthreads();

    // fold: NPB*128 = 512 outputs, 2 per thread; same output slot o for both
    // -> W1 column element loaded once per uu, reused across nodes
    const int o  = t & 127;
    const int nh = t >> 7;
    if (o < 32) {
        float ax[2] = {0.f, 0.f}, asc[2] = {0.f, 0.f};
#pragma unroll
        for (int uu = 0; uu < 32; ++uu) {
            const float w1 = W1_s[uu * 32 + o];
#pragma unroll
            for (int r2 = 0; r2 < 2; ++r2) {
                const int nn = nh + 2 * r2;
                const float s = nd[nn][uu];
                ax[r2]  += s * w1;
                asc[r2] += s * gs[nn][(uu << 5) + o];
            }
        }
#pragma unroll
        for (int r2 = 0; r2 < 2; ++r2) {
            const int nidx = nb + nh + 2 * r2;
            x[(size_t)nidx * 128 + 4 * o] = ax[r2] * INV_SQRT_MUL;
            out[(size_t)nidx * 128 + o]   = asc[r2] * NSC;
        }
    } else {
        const int q = o - 32;
        const int vch = q / 3, c = q - 3 * vch;
        float ax[2] = {0.f, 0.f}, asc[2] = {0.f, 0.f};
#pragma unroll
        for (int uu = 0; uu < 32; ++uu) {
            const float w1 = W1_v[uu * 32 + vch];
#pragma unroll
            for (int r2 = 0; r2 < 2; ++r2) {
                const int nn = nh + 2 * r2;
                const float vv = nd[nn][32 + 3 * uu + c];
                ax[r2]  += vv * w1;
                asc[r2] += vv * gv[nn][(uu << 5) + vch];
            }
        }
#pragma unroll
        for (int r2 = 0; r2 < 2; ++r2) {
            const int nidx = nb + nh + 2 * r2;
            x[(size_t)nidx * 128 + 4 * vch + 1 + c] = ax[r2] * INV_SQRT_MUL;
            out[(size_t)nidx * 128 + o]             = asc[r2] * NSC;
        }
    }
}

// ---------------------------------------------------------------------------
// K3a: per-block exclusive scan (1024 elems/block) + block sums
// ---------------------------------------------------------------------------
__global__ __launch_bounds__(1024) void k_scan_a(
    const int* __restrict__ counts, int* __restrict__ escan,
    int* __restrict__ bsum)
{
    __shared__ int sh[1024];
    const int t = threadIdx.x;
    const int i = blockIdx.x * 1024 + t;
    int v = (i < NN) ? counts[i] : 0;
    sh[t] = v;
    __syncthreads();
    for (int off = 1; off < 1024; off <<= 1) {
        int u = (t >= off) ? sh[t - off] : 0;
        __syncthreads();
        sh[t] += u;
        __syncthreads();
    }
    if (i < NN) escan[i] = sh[t] - v;
    if (t == 1023) bsum[blockIdx.x] = sh[1023];
}

// ---------------------------------------------------------------------------
// K3c (merged with old scan_b): each block computes its own bsum prefix
// (49 values, one wave reduction) then adds back -> offsets[N+1], cursor[N]
// ---------------------------------------------------------------------------
__global__ __launch_bounds__(1024) void k_scan_c(
    const int* __restrict__ escan, const int* __restrict__ bsum,
    int* __restrict__ offsets, int* __restrict__ cursor)
{
    __shared__ int sbase;
    const int t = threadIdx.x;
    if (t < 64) {
        int v = (t < blockIdx.x) ? bsum[t] : 0;   // blockIdx.x <= 48 < SCANB
        for (int off = 32; off > 0; off >>= 1) v += __shfl_xor(v, off, 64);
        if (t == 0) sbase = v;
    }
    __syncthreads();
    const int i = blockIdx.x * 1024 + t;
    if (i == 0) offsets[NN] = NE;
    if (i < NN) {
        int o = sbase + escan[i];
        offsets[i] = o;
        cursor[i] = o;
    }
}

// ---------------------------------------------------------------------------
// K4: pack — radial-MLP hidden h + 64B record at CSR position.
// record: [0]=src(bits) [1]=sh0 [2..4]=sh1 [5..12]=h [13..15]=pad
// ---------------------------------------------------------------------------
__global__ __launch_bounds__(256) void k_pack(
    const float* __restrict__ edge_emb, const float* __restrict__ edge_sh0,
    const float* __restrict__ edge_sh1,
    const int* __restrict__ edge_src, const int* __restrict__ edge_dst,
    const float* __restrict__ Wm1,
    int* __restrict__ cursor, float* __restrict__ epack)
{
    int e = blockIdx.x * 256 + threadIdx.x;
    if (e >= NE) return;
    const float4* p = (const float4*)(edge_emb + e * 8);
    float4 a = p[0], b = p[1];
    float emb[8] = {a.x, a.y, a.z, a.w, b.x, b.y, b.z, b.w};
    float h[8];
#pragma unroll
    for (int j = 0; j < 8; ++j) {
        float s = 0.f;
#pragma unroll
        for (int k = 0; k < 8; ++k) s += emb[k] * Wm1[k * 8 + j];
        s *= INV_SQRT_NEMB;
        h[j] = s * sigmoidf_(s);   // silu
    }
    float sh0 = edge_sh0[e];
    float sx = edge_sh1[3 * e], sy = edge_sh1[3 * e + 1], sz = edge_sh1[3 * e + 2];
    int src = edge_src[e];
    int pos = atomicAdd(&cursor[edge_dst[e]], 1);
    float4* op = (float4*)(epack + (size_t)pos * 16);
    op[0] = make_float4(__int_as_float(src), sh0, sx, sy);
    op[1] = make_float4(sz, h[0], h[1], h[2]);
    op[2] = make_float4(h[3], h[4], h[5], h[6]);
    op[3] = make_float4(h[7], 0.f, 0.f, 0.f);
}

// ---------------------------------------------------------------------------
// K5 (v6): one wave per node. Per-edge record read through WAVE-UNIFORM
// pointers -> scalar pipe (s_load) / broadcast dwordx4; NO LDS staging, NO
// per-chunk barriers. x-row gather is a single global_load_dwordx4 per lane
// (packed [u][{s,v0,v1,v2}] layout). Software-pipelined one edge ahead.
// Lane decomposition unchanged: u = L&31, role = L>>5.
// ---------------------------------------------------------------------------
__global__ __launch_bounds__(64) void k_gather(
    const float* __restrict__ x, const float* __restrict__ epack,
    const float* __restrict__ Wm2, const float* __restrict__ W2_s,
    const float* __restrict__ W2_v,
    const int* __restrict__ offsets, float* __restrict__ out)
{
    __shared__ float msg[352];
    const int n = blockIdx.x;
    const int L = threadIdx.x;
    const int u = L & 31;
    const int role = L >> 5;

    // Wm2 columns for this lane's paths: role0 -> {0,1,2}, role1 -> {3,4}
    float wc[3][8];
#pragma unroll
    for (int p = 0; p < 3; ++p) {
        int m = (role == 0 ? p : 3 + p) * 32 + u;
        if (m > 159) m = u;   // role1 third slot unused; keep in-bounds
#pragma unroll
        for (int q = 0; q < 8; ++q) wc[p][q] = Wm2[q * 160 + m];
    }

    float a0 = 0.f, a1 = 0.f;
    float b0 = 0.f, b1 = 0.f, b2 = 0.f;
    float c0 = 0.f, c1 = 0.f, c2 = 0.f;

    const int beg = offsets[n];
    const int end = offsets[n + 1];

    if (end > beg) {
        // preload record[beg] + its x row
        const float4* rp = (const float4*)(epack + (size_t)beg * 16);
        float4 r0 = rp[0];                  // (src, sh0, sx, sy)
        float4 r1 = rp[1];                  // (sz, h0, h1, h2)
        float4 r2 = rp[2];                  // (h3, h4, h5, h6)
        float  h7 = epack[(size_t)beg * 16 + 12];
        float4 xv = *(const float4*)(x + (size_t)__float_as_int(r0.x) * 128 + 4 * u);

        for (int e = beg; e < end; ++e) {
            // prefetch next record (clamped to stay in-bounds) + next x row
            const int ip = (e + 1 < end) ? (e + 1) : e;
            const float4* np = (const float4*)(epack + (size_t)ip * 16);
            const float4 q0 = np[0];
            const float4 q1 = np[1];
            const float4 q2 = np[2];
            const float  qh7 = epack[(size_t)ip * 16 + 12];
            const float4 nxv = *(const float4*)(x + (size_t)__float_as_int(q0.x) * 128 + 4 * u);

            const float sh0 = r0.y, sx = r0.z, sy = r0.w, sz = r1.x;
            float w0 = r1.y * wc[0][0] + r1.z * wc[0][1] + r1.w * wc[0][2]
                     + r2.x * wc[0][3] + r2.y * wc[0][4] + r2.z * wc[0][5]
                     + r2.w * wc[0][6] + h7  * wc[0][7];
            float w1 = r1.y * wc[1][0] + r1.z * wc[1][1] + r1.w * wc[1][2]
                     + r2.x * wc[1][3] + r2.y * wc[1][4] + r2.z * wc[1][5]
                     + r2.w * wc[1][6] + h7  * wc[1][7];
            float w2 = r1.y * wc[2][0] + r1.z * wc[2][1] + r1.w * wc[2][2]
                     + r2.x * wc[2][3] + r2.y * wc[2][4] + r2.z * wc[2][5]
                     + r2.w * wc[2][6] + h7  * wc[2][7];
            w0 *= INV_SQRT_HID; w1 *= INV_SQRT_HID; w2 *= INV_SQRT_HID;

            const float ls = xv.x, lv0 = xv.y, lv1 = xv.z, lv2 = xv.w;
            if (role == 0) {
                a0 += w0 * ls * sh0;
                a1 += w1 * (lv0 * sx + lv1 * sy + lv2 * sz);
                float tt = w2 * ls;
                b0 += tt * sx; b1 += tt * sy; b2 += tt * sz;
            } else {
                float t4 = w0 * sh0;
                b0 += t4 * lv0; b1 += t4 * lv1; b2 += t4 * lv2;
                c0 += w1 * (lv1 * sz - lv2 * sy);
                c1 += w1 * (lv2 * sx - lv0 * sz);
                c2 += w1 * (lv0 * sy - lv1 * sx);
            }
            r0 = q0; r1 = q1; r2 = q2; h7 = qh7;
            xv = nxv;
        }
    }

    // assemble msg[352]: [0..31]=p1, [32..63]=p2, [64+uu*3+c] uu=path*32+u
    if (role == 0) {
        msg[u]      = a0 * INV_NEIGH;
        msg[32 + u] = a1 * (INV3C * INV_NEIGH);
        int vb = 64 + u * 3;
        msg[vb]     = b0 * INV_NEIGH;
        msg[vb + 1] = b1 * INV_NEIGH;
        msg[vb + 2] = b2 * INV_NEIGH;
    } else {
        int vb4 = 64 + (32 + u) * 3;
        msg[vb4]     = b0 * INV_NEIGH;
        msg[vb4 + 1] = b1 * INV_NEIGH;
        msg[vb4 + 2] = b2 * INV_NEIGH;
        int vb5 = 64 + (64 + u) * 3;
        float f = INV2C * INV_NEIGH;
        msg[vb5]     = c0 * f;
        msg[vb5 + 1] = c1 * f;
        msg[vb5 + 2] = c2 * f;
    }
    __syncthreads();

    // fold linear_2, add to self-connection already in out
#pragma unroll
    for (int oo = 0; oo < 2; ++oo) {
        int o = oo * 64 + L;
        float r;
        if (o < 32) {
            float s = 0.f;
#pragma unroll
            for (int uu = 0; uu < 64; ++uu) s += msg[uu] * W2_s[uu * 32 + o];
            r = s * INV_SQRT_2MUL;
        } else {
            int q = o - 32;
            int vch = q / 3, c = q - 3 * vch;
            float s = 0.f;
#pragma unroll
            for (int uu = 0; uu < 96; ++uu) s += msg[64 + uu * 3 + c] * W2_v[uu * 32 + vch];
            r = s * INV_SQRT_3MUL;
        }
        out[128 * n + o] += r;
    }
}

// ---------------------------------------------------------------------------
extern "C" void kernel_launch(void* const* d_in, const int* in_sizes, int n_in,
                              void* d_out, int out_size, void* d_ws, size_t ws_size,
                              hipStream_t stream) {
    const float* node_s   = (const float*)d_in[0];
    const float* node_v   = (const float*)d_in[1];
    const float* attrs    = (const float*)d_in[2];
    const float* edge_emb = (const float*)d_in[3];
    const float* edge_sh0 = (const float*)d_in[4];
    const float* edge_sh1 = (const float*)d_in[5];
    const float* W1_s     = (const float*)d_in[6];
    const float* W1_v     = (const float*)d_in[7];
    const float* Wm1      = (const float*)d_in[8];
    const float* Wm2      = (const float*)d_in[9];
    const float* W2_s     = (const float*)d_in[10];
    const float* W2_v     = (const float*)d_in[11];
    const float* Wsc_s    = (const float*)d_in[12];
    const float* Wsc_v    = (const float*)d_in[13];
    const int*   edge_src = (const int*)d_in[14];
    const int*   edge_dst = (const int*)d_in[15];
    float* out = (float*)d_out;

    // workspace layout (unchanged)
    float* x     = (float*)d_ws;                     // N*128
    float* epack = x + (size_t)NN * 128;             // E*16
    int*   counts  = (int*)(epack + (size_t)NE * 16);// N
    int*   offsets = counts + NN;                    // N+1
    int*   cursor  = offsets + NN + 1;               // N
    int*   escan   = cursor + NN;                    // N
    int*   bsum    = escan + NN;                     // SCANB

    hipMemsetAsync(counts, 0, NN * sizeof(int), stream);

    k_node<<<NN / NPB, 256, 0, stream>>>(node_s, node_v, attrs,
                                         W1_s, W1_v, Wsc_s, Wsc_v,
                                         edge_dst, counts, x, out);
    k_scan_a<<<SCANB, 1024, 0, stream>>>(counts, escan, bsum);
    k_scan_c<<<SCANB, 1024, 0, stream>>>(escan, bsum, offsets, cursor);
    k_pack<<<(NE + 255) / 256, 256, 0, stream>>>(edge_emb, edge_sh0, edge_sh1,
                                                 edge_src, edge_dst, Wm1,
                                                 cursor, epack);
    k_gather<<<NN, 64, 0, stream>>>(x, epack, Wm2, W2_s, W2_v, offsets, out);
}

// Round 4
// 411.715 us; speedup vs baseline: 1.2098x; 1.0127x over previous
//
#include <hip/hip_runtime.h>
#include <math.h>

#define NN 50000
#define NE 800000
#define MUL 32
#define NPB 4       /* nodes per k_node block */
#define SCANB 49    /* ceil(NN/1024) */

static __device__ __forceinline__ float sigmoidf_(float v) {
    return 1.0f / (1.0f + __expf(-v));
}

#define INV_SQRT_MUL   0.17677669529663687f   /* 1/sqrt(32) */
#define INV_SQRT_NEMB  0.35355339059327373f   /* 1/sqrt(8)  */
#define INV_SQRT_HID   0.35355339059327373f   /* 1/sqrt(8)  */
#define INV3C          0.5773502691896258f    /* 1/sqrt(3)  */
#define INV2C          0.7071067811865476f    /* 1/sqrt(2)  */
#define INV_NEIGH      0.25f                  /* 1/sqrt(16) */
#define INV_SQRT_2MUL  0.125f                 /* 1/sqrt(64) */
#define INV_SQRT_3MUL  0.10206207261596575f   /* 1/sqrt(96) */
#define NSC            0.0625f                /* 1/sqrt(32*8) */

// ---------------------------------------------------------------------------
// K1 (unchanged from v6): NPB=4 nodes/block, Wsc loaded once per block,
// fused dst histogram. x layout packed-per-u:
//   x[n*128 + 4*u + 0] = s[u],  x[n*128 + 4*u + 1 + c] = v[u][c]
// ---------------------------------------------------------------------------
__global__ __launch_bounds__(256) void k_node(
    const float* __restrict__ node_s, const float* __restrict__ node_v,
    const float* __restrict__ attrs,
    const float* __restrict__ W1_s, const float* __restrict__ W1_v,
    const float* __restrict__ Wsc_s, const float* __restrict__ Wsc_v,
    const int* __restrict__ edge_dst, int* __restrict__ counts,
    float* __restrict__ x, float* __restrict__ out)
{
    __shared__ float nd[NPB][136];
    __shared__ float gs[NPB][1024];
    __shared__ float gv[NPB][1024];
    const int t  = threadIdx.x;
    const int nb = blockIdx.x * NPB;

    {
        int g = blockIdx.x * 256 + t;
        if (g < NE) atomicAdd(&counts[edge_dst[g]], 1);
    }

#pragma unroll
    for (int i = t; i < NPB * 128; i += 256) {
        int nn = i >> 7, j = i & 127;
        nd[nn][j] = (j < 32) ? node_s[(nb + nn) * 32 + j]
                             : node_v[(nb + nn) * 96 + (j - 32)];
    }
    if (t < NPB * 8) nd[t >> 3][128 + (t & 7)] = attrs[(nb + (t >> 3)) * 8 + (t & 7)];
    __syncthreads();

    float at[NPB][8];
#pragma unroll
    for (int nn = 0; nn < NPB; ++nn)
#pragma unroll
        for (int a = 0; a < 8; ++a) at[nn][a] = nd[nn][128 + a];

#pragma unroll
    for (int r = 0; r < 4; ++r) {
        const int idx = t + 256 * r;
        const int u = idx >> 5, vch = idx & 31;
        float as[NPB] = {0.f, 0.f, 0.f, 0.f};
        float av[NPB] = {0.f, 0.f, 0.f, 0.f};
#pragma unroll
        for (int a = 0; a < 8; ++a) {
            const float ws = Wsc_s[(u * 8 + a) * 32 + vch];
            const float wvw = Wsc_v[(u * 8 + a) * 32 + vch];
#pragma unroll
            for (int nn = 0; nn < NPB; ++nn) {
                as[nn] += at[nn][a] * ws;
                av[nn] += at[nn][a] * wvw;
            }
        }
#pragma unroll
        for (int nn = 0; nn < NPB; ++nn) {
            gs[nn][idx] = as[nn];
            gv[nn][idx] = av[nn];
        }
    }
    __syncthreads();

    const int o  = t & 127;
    const int nh = t >> 7;
    if (o < 32) {
        float ax[2] = {0.f, 0.f}, asc[2] = {0.f, 0.f};
#pragma unroll
        for (int uu = 0; uu < 32; ++uu) {
            const float w1 = W1_s[uu * 32 + o];
#pragma unroll
            for (int r2 = 0; r2 < 2; ++r2) {
                const int nn = nh + 2 * r2;
                const float s = nd[nn][uu];
                ax[r2]  += s * w1;
                asc[r2] += s * gs[nn][(uu << 5) + o];
            }
        }
#pragma unroll
        for (int r2 = 0; r2 < 2; ++r2) {
            const int nidx = nb + nh + 2 * r2;
            x[(size_t)nidx * 128 + 4 * o] = ax[r2] * INV_SQRT_MUL;
            out[(size_t)nidx * 128 + o]   = asc[r2] * NSC;
        }
    } else {
        const int q = o - 32;
        const int vch = q / 3, c = q - 3 * vch;
        float ax[2] = {0.f, 0.f}, asc[2] = {0.f, 0.f};
#pragma unroll
        for (int uu = 0; uu < 32; ++uu) {
            const float w1 = W1_v[uu * 32 + vch];
#pragma unroll
            for (int r2 = 0; r2 < 2; ++r2) {
                const int nn = nh + 2 * r2;
                const float vv = nd[nn][32 + 3 * uu + c];
                ax[r2]  += vv * w1;
                asc[r2] += vv * gv[nn][(uu << 5) + vch];
            }
        }
#pragma unroll
        for (int r2 = 0; r2 < 2; ++r2) {
            const int nidx = nb + nh + 2 * r2;
            x[(size_t)nidx * 128 + 4 * vch + 1 + c] = ax[r2] * INV_SQRT_MUL;
            out[(size_t)nidx * 128 + o]             = asc[r2] * NSC;
        }
    }
}

// ---------------------------------------------------------------------------
// K3a: per-block exclusive scan (1024 elems/block) + block sums
// ---------------------------------------------------------------------------
__global__ __launch_bounds__(1024) void k_scan_a(
    const int* __restrict__ counts, int* __restrict__ escan,
    int* __restrict__ bsum)
{
    __shared__ int sh[1024];
    const int t = threadIdx.x;
    const int i = blockIdx.x * 1024 + t;
    int v = (i < NN) ? counts[i] : 0;
    sh[t] = v;
    __syncthreads();
    for (int off = 1; off < 1024; off <<= 1) {
        int u = (t >= off) ? sh[t - off] : 0;
        __syncthreads();
        sh[t] += u;
        __syncthreads();
    }
    if (i < NN) escan[i] = sh[t] - v;
    if (t == 1023) bsum[blockIdx.x] = sh[1023];
}

// ---------------------------------------------------------------------------
// K3c: per-block bsum prefix + add-back -> offsets[N+1], cursor[N]
// ---------------------------------------------------------------------------
__global__ __launch_bounds__(1024) void k_scan_c(
    const int* __restrict__ escan, const int* __restrict__ bsum,
    int* __restrict__ offsets, int* __restrict__ cursor)
{
    __shared__ int sbase;
    const int t = threadIdx.x;
    if (t < 64) {
        int v = (t < blockIdx.x) ? bsum[t] : 0;
        for (int off = 32; off > 0; off >>= 1) v += __shfl_xor(v, off, 64);
        if (t == 0) sbase = v;
    }
    __syncthreads();
    const int i = blockIdx.x * 1024 + t;
    if (i == 0) offsets[NN] = NE;
    if (i < NN) {
        int o = sbase + escan[i];
        offsets[i] = o;
        cursor[i] = o;
    }
}

// ---------------------------------------------------------------------------
// K4: pack — radial-MLP hidden h + 64B record at CSR position.
// record: [0]=src(bits) [1]=sh0 [2..4]=sh1 [5..12]=h [13..15]=pad
// ---------------------------------------------------------------------------
__global__ __launch_bounds__(256) void k_pack(
    const float* __restrict__ edge_emb, const float* __restrict__ edge_sh0,
    const float* __restrict__ edge_sh1,
    const int* __restrict__ edge_src, const int* __restrict__ edge_dst,
    const float* __restrict__ Wm1,
    int* __restrict__ cursor, float* __restrict__ epack)
{
    int e = blockIdx.x * 256 + threadIdx.x;
    if (e >= NE) return;
    const float4* p = (const float4*)(edge_emb + e * 8);
    float4 a = p[0], b = p[1];
    float emb[8] = {a.x, a.y, a.z, a.w, b.x, b.y, b.z, b.w};
    float h[8];
#pragma unroll
    for (int j = 0; j < 8; ++j) {
        float s = 0.f;
#pragma unroll
        for (int k = 0; k < 8; ++k) s += emb[k] * Wm1[k * 8 + j];
        s *= INV_SQRT_NEMB;
        h[j] = s * sigmoidf_(s);
    }
    float sh0 = edge_sh0[e];
    float sx = edge_sh1[3 * e], sy = edge_sh1[3 * e + 1], sz = edge_sh1[3 * e + 2];
    int src = edge_src[e];
    int pos = atomicAdd(&cursor[edge_dst[e]], 1);
    float4* op = (float4*)(epack + (size_t)pos * 16);
    op[0] = make_float4(__int_as_float(src), sh0, sx, sy);
    op[1] = make_float4(sz, h[0], h[1], h[2]);
    op[2] = make_float4(h[3], h[4], h[5], h[6]);
    op[3] = make_float4(h[7], 0.f, 0.f, 0.f);
}

// ---------------------------------------------------------------------------
// K5 (v7): 256-thread block = 4 waves = 4 nodes.
// Edge loop: TWO edges per iteration — half-wave 0 takes even edge, half-wave
// 1 the odd edge; every lane computes all 5 paths for ITS edge (no role
// divergence). Odd tail handled by zeroing sh for half 1 (all paths linear in
// sh). Cross-half combine via __shfl_xor(...,32).
// Fold: divergence-free block-cooperative linear_2 with W2 staged in LDS once
// per block; msg vectors stored as c-major planes [64 + c*96 + uu] so each
// v-thread computes a full 3-vector (weight read amortized over 3 MACs).
// ---------------------------------------------------------------------------
__global__ __launch_bounds__(256) void k_gather(
    const float* __restrict__ x, const float* __restrict__ epack,
    const float* __restrict__ Wm2, const float* __restrict__ W2_s,
    const float* __restrict__ W2_v,
    const int* __restrict__ offsets, float* __restrict__ out)
{
    __shared__ __align__(16) float wsh[2048];   // W2_s
    __shared__ __align__(16) float wvh[3072];   // W2_v
    __shared__ float msg[4][360];               // per-wave message, padded

    // stage W2 into LDS (visible after the pre-fold barrier)
    for (int i = threadIdx.x; i < 512; i += 256)
        ((float4*)wsh)[i] = ((const float4*)W2_s)[i];
    for (int i = threadIdx.x; i < 768; i += 256)
        ((float4*)wvh)[i] = ((const float4*)W2_v)[i];

    const int w    = threadIdx.x >> 6;       // wave id = node within block
    const int L    = threadIdx.x & 63;
    const int u    = L & 31;
    const int half = L >> 5;
    const int n    = blockIdx.x * 4 + w;     // NN = 50000 = 12500*4, always valid

    // per-lane Wm2 columns for ALL 5 paths (role-independent), pre-scaled
    float wc[5][8];
#pragma unroll
    for (int p = 0; p < 5; ++p)
#pragma unroll
        for (int q = 0; q < 8; ++q)
            wc[p][q] = Wm2[q * 160 + p * 32 + u] * INV_SQRT_HID;

    float pa = 0.f, pb = 0.f;
    float p30 = 0.f, p31 = 0.f, p32 = 0.f;
    float p40 = 0.f, p41 = 0.f, p42 = 0.f;
    float p50 = 0.f, p51 = 0.f, p52 = 0.f;

    const int beg = offsets[n];
    const int end = offsets[n + 1];
    const int cnt = end - beg;

#define EDGE_BODY() do { \
        const float sh0 = r0.y, sx = r0.z, sy = r0.w, sz = r1.x; \
        const float w0 = r1.y*wc[0][0] + r1.z*wc[0][1] + r1.w*wc[0][2] + r2.x*wc[0][3] \
                       + r2.y*wc[0][4] + r2.z*wc[0][5] + r2.w*wc[0][6] + h7*wc[0][7]; \
        const float w1 = r1.y*wc[1][0] + r1.z*wc[1][1] + r1.w*wc[1][2] + r2.x*wc[1][3] \
                       + r2.y*wc[1][4] + r2.z*wc[1][5] + r2.w*wc[1][6] + h7*wc[1][7]; \
        const float w2 = r1.y*wc[2][0] + r1.z*wc[2][1] + r1.w*wc[2][2] + r2.x*wc[2][3] \
                       + r2.y*wc[2][4] + r2.z*wc[2][5] + r2.w*wc[2][6] + h7*wc[2][7]; \
        const float w3 = r1.y*wc[3][0] + r1.z*wc[3][1] + r1.w*wc[3][2] + r2.x*wc[3][3] \
                       + r2.y*wc[3][4] + r2.z*wc[3][5] + r2.w*wc[3][6] + h7*wc[3][7]; \
        const float w4 = r1.y*wc[4][0] + r1.z*wc[4][1] + r1.w*wc[4][2] + r2.x*wc[4][3] \
                       + r2.y*wc[4][4] + r2.z*wc[4][5] + r2.w*wc[4][6] + h7*wc[4][7]; \
        const float ls = xv.x, lv0 = xv.y, lv1 = xv.z, lv2 = xv.w; \
        pa += w0 * (ls * sh0); \
        pb += w1 * (lv0 * sx + lv1 * sy + lv2 * sz); \
        const float t2 = w2 * ls; \
        p30 += t2 * sx; p31 += t2 * sy; p32 += t2 * sz; \
        const float t3 = w3 * sh0; \
        p40 += t3 * lv0; p41 += t3 * lv1; p42 += t3 * lv2; \
        p50 += w4 * (lv1 * sz - lv2 * sy); \
        p51 += w4 * (lv2 * sx - lv0 * sz); \
        p52 += w4 * (lv0 * sy - lv1 * sx); \
    } while (0)

    if (cnt > 0) {
        int e = beg + half;                       // this lane's edge
        int le = min(e, end - 1);
        const float4* rp = (const float4*)(epack + (size_t)le * 16);
        float4 r0 = rp[0], r1 = rp[1], r2 = rp[2];
        float  h7 = epack[(size_t)le * 16 + 12];
        float4 xv = *(const float4*)(x + (size_t)__float_as_int(r0.x) * 128 + 4 * u);

        const int np = cnt >> 1;
        for (int it = 0; it < np; ++it) {
            const int pe = min(e + 2, end - 1);   // clamped prefetch (feeds tail)
            const float4* qp = (const float4*)(epack + (size_t)pe * 16);
            const float4 q0 = qp[0], q1 = qp[1], q2 = qp[2];
            const float  qh7 = epack[(size_t)pe * 16 + 12];
            const float4 nxv = *(const float4*)(x + (size_t)__float_as_int(q0.x) * 128 + 4 * u);

            EDGE_BODY();

            r0 = q0; r1 = q1; r2 = q2; h7 = qh7; xv = nxv;
            e += 2;
        }
        if (cnt & 1) {
            // r* hold record end-1 for both halves; zero sh for half 1
            const float mask = (half == 0) ? 1.f : 0.f;
            r0.y *= mask; r0.z *= mask; r0.w *= mask; r1.x *= mask;
            EDGE_BODY();
        }
    }
#undef EDGE_BODY

    // combine even/odd-edge partials across halves
    pa  += __shfl_xor(pa, 32);  pb  += __shfl_xor(pb, 32);
    p30 += __shfl_xor(p30, 32); p31 += __shfl_xor(p31, 32); p32 += __shfl_xor(p32, 32);
    p40 += __shfl_xor(p40, 32); p41 += __shfl_xor(p41, 32); p42 += __shfl_xor(p42, 32);
    p50 += __shfl_xor(p50, 32); p51 += __shfl_xor(p51, 32); p52 += __shfl_xor(p52, 32);

    // msg layout: [0..31]=p1, [32..63]=p2, vectors c-major: [64 + c*96 + uu],
    // uu = (path-3)*32 + u
    {
        float* mg = msg[w];
        if (half == 0) {
            mg[u]              = pa  * INV_NEIGH;
            mg[32 + u]         = pb  * (INV3C * INV_NEIGH);
            mg[64 + u]         = p30 * INV_NEIGH;
            mg[64 + 96 + u]    = p31 * INV_NEIGH;
            mg[64 + 192 + u]   = p32 * INV_NEIGH;
        } else {
            mg[64 + 32 + u]        = p40 * INV_NEIGH;
            mg[64 + 96 + 32 + u]   = p41 * INV_NEIGH;
            mg[64 + 192 + 32 + u]  = p42 * INV_NEIGH;
            const float f = INV2C * INV_NEIGH;
            mg[64 + 64 + u]        = p50 * f;
            mg[64 + 96 + 64 + u]   = p51 * f;
            mg[64 + 192 + 64 + u]  = p52 * f;
        }
    }
    __syncthreads();

    // divergence-free cooperative fold of linear_2 for the block's 4 nodes
    {
        const int nb = blockIdx.x * 4;
        const int t = threadIdx.x;
        if (t < 128) {
            const int node = t >> 5, o = t & 31;
            float s = 0.f;
#pragma unroll
            for (int uu = 0; uu < 64; ++uu) s += msg[node][uu] * wsh[uu * 32 + o];
            out[(size_t)(nb + node) * 128 + o] += s * INV_SQRT_2MUL;
        } else {
            const int node = (t - 128) >> 5, vch = t & 31;
            float s0 = 0.f, s1 = 0.f, s2 = 0.f;
#pragma unroll
            for (int uu = 0; uu < 96; ++uu) {
                const float wgt = wvh[uu * 32 + vch];
                s0 += msg[node][64 + uu]       * wgt;
                s1 += msg[node][64 + 96 + uu]  * wgt;
                s2 += msg[node][64 + 192 + uu] * wgt;
            }
            float* po = out + (size_t)(nb + node) * 128 + 32 + vch * 3;
            po[0] += s0 * INV_SQRT_3MUL;
            po[1] += s1 * INV_SQRT_3MUL;
            po[2] += s2 * INV_SQRT_3MUL;
        }
    }
}

// ---------------------------------------------------------------------------
extern "C" void kernel_launch(void* const* d_in, const int* in_sizes, int n_in,
                              void* d_out, int out_size, void* d_ws, size_t ws_size,
                              hipStream_t stream) {
    const float* node_s   = (const float*)d_in[0];
    const float* node_v   = (const float*)d_in[1];
    const float* attrs    = (const float*)d_in[2];
    const float* edge_emb = (const float*)d_in[3];
    const float* edge_sh0 = (const float*)d_in[4];
    const float* edge_sh1 = (const float*)d_in[5];
    const float* W1_s     = (const float*)d_in[6];
    const float* W1_v     = (const float*)d_in[7];
    const float* Wm1      = (const float*)d_in[8];
    const float* Wm2      = (const float*)d_in[9];
    const float* W2_s     = (const float*)d_in[10];
    const float* W2_v     = (const float*)d_in[11];
    const float* Wsc_s    = (const float*)d_in[12];
    const float* Wsc_v    = (const float*)d_in[13];
    const int*   edge_src = (const int*)d_in[14];
    const int*   edge_dst = (const int*)d_in[15];
    float* out = (float*)d_out;

    // workspace layout (unchanged)
    float* x     = (float*)d_ws;                     // N*128
    float* epack = x + (size_t)NN * 128;             // E*16
    int*   counts  = (int*)(epack + (size_t)NE * 16);// N
    int*   offsets = counts + NN;                    // N+1
    int*   cursor  = offsets + NN + 1;               // N
    int*   escan   = cursor + NN;                    // N
    int*   bsum    = escan + NN;                     // SCANB

    hipMemsetAsync(counts, 0, NN * sizeof(int), stream);

    k_node<<<NN / NPB, 256, 0, stream>>>(node_s, node_v, attrs,
                                         W1_s, W1_v, Wsc_s, Wsc_v,
                                         edge_dst, counts, x, out);
    k_scan_a<<<SCANB, 1024, 0, stream>>>(counts, escan, bsum);
    k_scan_c<<<SCANB, 1024, 0, stream>>>(escan, bsum, offsets, cursor);
    k_pack<<<(NE + 255) / 256, 256, 0, stream>>>(edge_emb, edge_sh0, edge_sh1,
                                                 edge_src, edge_dst, Wm1,
                                                 cursor, epack);
    k_gather<<<NN / 4, 256, 0, stream>>>(x, epack, Wm2, W2_s, W2_v,
                                         offsets, out);
}

// Round 5
// 406.740 us; speedup vs baseline: 1.2246x; 1.0122x over previous
//
#include <hip/hip_runtime.h>
#include <math.h>

#define NN 50000
#define NE 800000
#define MUL 32
#define NPB 4       /* nodes per k_node block */
#define SCANB 49    /* ceil(NN/1024) */

static __device__ __forceinline__ float sigmoidf_(float v) {
    return 1.0f / (1.0f + __expf(-v));
}

#define INV_SQRT_MUL   0.17677669529663687f   /* 1/sqrt(32) */
#define INV_SQRT_NEMB  0.35355339059327373f   /* 1/sqrt(8)  */
#define INV_SQRT_HID   0.35355339059327373f   /* 1/sqrt(8)  */
#define INV3C          0.5773502691896258f    /* 1/sqrt(3)  */
#define INV2C          0.7071067811865476f    /* 1/sqrt(2)  */
#define INV_NEIGH      0.25f                  /* 1/sqrt(16) */
#define INV_SQRT_2MUL  0.125f                 /* 1/sqrt(64) */
#define INV_SQRT_3MUL  0.10206207261596575f   /* 1/sqrt(96) */
#define NSC            0.0625f                /* 1/sqrt(32*8) */

// ---------------------------------------------------------------------------
// K1 (unchanged): NPB=4 nodes/block, Wsc loaded once per block, fused dst
// histogram. x layout packed-per-u:
//   x[n*128 + 4*u + 0] = s[u],  x[n*128 + 4*u + 1 + c] = v[u][c]
// ---------------------------------------------------------------------------
__global__ __launch_bounds__(256) void k_node(
    const float* __restrict__ node_s, const float* __restrict__ node_v,
    const float* __restrict__ attrs,
    const float* __restrict__ W1_s, const float* __restrict__ W1_v,
    const float* __restrict__ Wsc_s, const float* __restrict__ Wsc_v,
    const int* __restrict__ edge_dst, int* __restrict__ counts,
    float* __restrict__ x, float* __restrict__ out)
{
    __shared__ float nd[NPB][136];
    __shared__ float gs[NPB][1024];
    __shared__ float gv[NPB][1024];
    const int t  = threadIdx.x;
    const int nb = blockIdx.x * NPB;

    {
        int g = blockIdx.x * 256 + t;
        if (g < NE) atomicAdd(&counts[edge_dst[g]], 1);
    }

#pragma unroll
    for (int i = t; i < NPB * 128; i += 256) {
        int nn = i >> 7, j = i & 127;
        nd[nn][j] = (j < 32) ? node_s[(nb + nn) * 32 + j]
                             : node_v[(nb + nn) * 96 + (j - 32)];
    }
    if (t < NPB * 8) nd[t >> 3][128 + (t & 7)] = attrs[(nb + (t >> 3)) * 8 + (t & 7)];
    __syncthreads();

    float at[NPB][8];
#pragma unroll
    for (int nn = 0; nn < NPB; ++nn)
#pragma unroll
        for (int a = 0; a < 8; ++a) at[nn][a] = nd[nn][128 + a];

#pragma unroll
    for (int r = 0; r < 4; ++r) {
        const int idx = t + 256 * r;
        const int u = idx >> 5, vch = idx & 31;
        float as[NPB] = {0.f, 0.f, 0.f, 0.f};
        float av[NPB] = {0.f, 0.f, 0.f, 0.f};
#pragma unroll
        for (int a = 0; a < 8; ++a) {
            const float ws = Wsc_s[(u * 8 + a) * 32 + vch];
            const float wvw = Wsc_v[(u * 8 + a) * 32 + vch];
#pragma unroll
            for (int nn = 0; nn < NPB; ++nn) {
                as[nn] += at[nn][a] * ws;
                av[nn] += at[nn][a] * wvw;
            }
        }
#pragma unroll
        for (int nn = 0; nn < NPB; ++nn) {
            gs[nn][idx] = as[nn];
            gv[nn][idx] = av[nn];
        }
    }
    __syncthreads();

    const int o  = t & 127;
    const int nh = t >> 7;
    if (o < 32) {
        float ax[2] = {0.f, 0.f}, asc[2] = {0.f, 0.f};
#pragma unroll
        for (int uu = 0; uu < 32; ++uu) {
            const float w1 = W1_s[uu * 32 + o];
#pragma unroll
            for (int r2 = 0; r2 < 2; ++r2) {
                const int nn = nh + 2 * r2;
                const float s = nd[nn][uu];
                ax[r2]  += s * w1;
                asc[r2] += s * gs[nn][(uu << 5) + o];
            }
        }
#pragma unroll
        for (int r2 = 0; r2 < 2; ++r2) {
            const int nidx = nb + nh + 2 * r2;
            x[(size_t)nidx * 128 + 4 * o] = ax[r2] * INV_SQRT_MUL;
            out[(size_t)nidx * 128 + o]   = asc[r2] * NSC;
        }
    } else {
        const int q = o - 32;
        const int vch = q / 3, c = q - 3 * vch;
        float ax[2] = {0.f, 0.f}, asc[2] = {0.f, 0.f};
#pragma unroll
        for (int uu = 0; uu < 32; ++uu) {
            const float w1 = W1_v[uu * 32 + vch];
#pragma unroll
            for (int r2 = 0; r2 < 2; ++r2) {
                const int nn = nh + 2 * r2;
                const float vv = nd[nn][32 + 3 * uu + c];
                ax[r2]  += vv * w1;
                asc[r2] += vv * gv[nn][(uu << 5) + vch];
            }
        }
#pragma unroll
        for (int r2 = 0; r2 < 2; ++r2) {
            const int nidx = nb + nh + 2 * r2;
            x[(size_t)nidx * 128 + 4 * vch + 1 + c] = ax[r2] * INV_SQRT_MUL;
            out[(size_t)nidx * 128 + o]             = asc[r2] * NSC;
        }
    }
}

// ---------------------------------------------------------------------------
// K3a: per-block exclusive scan (1024 elems/block) + block sums
// ---------------------------------------------------------------------------
__global__ __launch_bounds__(1024) void k_scan_a(
    const int* __restrict__ counts, int* __restrict__ escan,
    int* __restrict__ bsum)
{
    __shared__ int sh[1024];
    const int t = threadIdx.x;
    const int i = blockIdx.x * 1024 + t;
    int v = (i < NN) ? counts[i] : 0;
    sh[t] = v;
    __syncthreads();
    for (int off = 1; off < 1024; off <<= 1) {
        int u = (t >= off) ? sh[t - off] : 0;
        __syncthreads();
        sh[t] += u;
        __syncthreads();
    }
    if (i < NN) escan[i] = sh[t] - v;
    if (t == 1023) bsum[blockIdx.x] = sh[1023];
}

// ---------------------------------------------------------------------------
// K3c: per-block bsum prefix + add-back -> offsets[N+1], cursor[N]
// ---------------------------------------------------------------------------
__global__ __launch_bounds__(1024) void k_scan_c(
    const int* __restrict__ escan, const int* __restrict__ bsum,
    int* __restrict__ offsets, int* __restrict__ cursor)
{
    __shared__ int sbase;
    const int t = threadIdx.x;
    if (t < 64) {
        int v = (t < blockIdx.x) ? bsum[t] : 0;
        for (int off = 32; off > 0; off >>= 1) v += __shfl_xor(v, off, 64);
        if (t == 0) sbase = v;
    }
    __syncthreads();
    const int i = blockIdx.x * 1024 + t;
    if (i == 0) offsets[NN] = NE;
    if (i < NN) {
        int o = sbase + escan[i];
        offsets[i] = o;
        cursor[i] = o;
    }
}

// ---------------------------------------------------------------------------
// K4: pack — radial-MLP hidden h + 64B record at CSR position.
// record: [0]=src(bits) [1]=sh0 [2..4]=sh1 [5..12]=h [13..15]=pad
// ---------------------------------------------------------------------------
__global__ __launch_bounds__(256) void k_pack(
    const float* __restrict__ edge_emb, const float* __restrict__ edge_sh0,
    const float* __restrict__ edge_sh1,
    const int* __restrict__ edge_src, const int* __restrict__ edge_dst,
    const float* __restrict__ Wm1,
    int* __restrict__ cursor, float* __restrict__ epack)
{
    int e = blockIdx.x * 256 + threadIdx.x;
    if (e >= NE) return;
    const float4* p = (const float4*)(edge_emb + e * 8);
    float4 a = p[0], b = p[1];
    float emb[8] = {a.x, a.y, a.z, a.w, b.x, b.y, b.z, b.w};
    float h[8];
#pragma unroll
    for (int j = 0; j < 8; ++j) {
        float s = 0.f;
#pragma unroll
        for (int k = 0; k < 8; ++k) s += emb[k] * Wm1[k * 8 + j];
        s *= INV_SQRT_NEMB;
        h[j] = s * sigmoidf_(s);
    }
    float sh0 = edge_sh0[e];
    float sx = edge_sh1[3 * e], sy = edge_sh1[3 * e + 1], sz = edge_sh1[3 * e + 2];
    int src = edge_src[e];
    int pos = atomicAdd(&cursor[edge_dst[e]], 1);
    float4* op = (float4*)(epack + (size_t)pos * 16);
    op[0] = make_float4(__int_as_float(src), sh0, sx, sy);
    op[1] = make_float4(sz, h[0], h[1], h[2]);
    op[2] = make_float4(h[3], h[4], h[5], h[6]);
    op[3] = make_float4(h[7], 0.f, 0.f, 0.f);
}

// ---------------------------------------------------------------------------
// K5 (v8): 256-thread block = 4 waves = 4 nodes. v7 structure, minus the W2
// LDS staging (W2 is 20KB, coalesced + wave-repeating -> L1-resident; the
// staging cost 20KB LDS and capped occupancy at 6 blocks/CU, measured 39%).
// LDS now 5.76KB (msg only) -> occupancy VGPR-bound (~8 blocks/CU).
// Edge loop: pointer-walk addressing; steady loop runs np-1 clean iterations
// (prefetch provably in-bounds), last pair + odd tail handled in epilogue.
// ---------------------------------------------------------------------------
__global__ __launch_bounds__(256) void k_gather(
    const float* __restrict__ x, const float* __restrict__ epack,
    const float* __restrict__ Wm2, const float* __restrict__ W2_s,
    const float* __restrict__ W2_v,
    const int* __restrict__ offsets, float* __restrict__ out)
{
    __shared__ float msg[4][360];               // per-wave message, padded

    const int w    = threadIdx.x >> 6;       // wave id = node within block
    const int L    = threadIdx.x & 63;
    const int u    = L & 31;
    const int half = L >> 5;
    const int n    = blockIdx.x * 4 + w;     // NN = 50000 = 12500*4, always valid

    // per-lane Wm2 columns for ALL 5 paths (role-independent), pre-scaled
    float wc[5][8];
#pragma unroll
    for (int p = 0; p < 5; ++p)
#pragma unroll
        for (int q = 0; q < 8; ++q)
            wc[p][q] = Wm2[q * 160 + p * 32 + u] * INV_SQRT_HID;

    float pa = 0.f, pb = 0.f;
    float p30 = 0.f, p31 = 0.f, p32 = 0.f;
    float p40 = 0.f, p41 = 0.f, p42 = 0.f;
    float p50 = 0.f, p51 = 0.f, p52 = 0.f;

    const int beg = offsets[n];
    const int end = offsets[n + 1];
    const int cnt = end - beg;

#define EDGE_BODY() do { \
        const float sh0 = r0.y, sx = r0.z, sy = r0.w, sz = r1.x; \
        const float w0 = r1.y*wc[0][0] + r1.z*wc[0][1] + r1.w*wc[0][2] + r2.x*wc[0][3] \
                       + r2.y*wc[0][4] + r2.z*wc[0][5] + r2.w*wc[0][6] + h7*wc[0][7]; \
        const float w1 = r1.y*wc[1][0] + r1.z*wc[1][1] + r1.w*wc[1][2] + r2.x*wc[1][3] \
                       + r2.y*wc[1][4] + r2.z*wc[1][5] + r2.w*wc[1][6] + h7*wc[1][7]; \
        const float w2 = r1.y*wc[2][0] + r1.z*wc[2][1] + r1.w*wc[2][2] + r2.x*wc[2][3] \
                       + r2.y*wc[2][4] + r2.z*wc[2][5] + r2.w*wc[2][6] + h7*wc[2][7]; \
        const float w3 = r1.y*wc[3][0] + r1.z*wc[3][1] + r1.w*wc[3][2] + r2.x*wc[3][3] \
                       + r2.y*wc[3][4] + r2.z*wc[3][5] + r2.w*wc[3][6] + h7*wc[3][7]; \
        const float w4 = r1.y*wc[4][0] + r1.z*wc[4][1] + r1.w*wc[4][2] + r2.x*wc[4][3] \
                       + r2.y*wc[4][4] + r2.z*wc[4][5] + r2.w*wc[4][6] + h7*wc[4][7]; \
        const float ls = xv.x, lv0 = xv.y, lv1 = xv.z, lv2 = xv.w; \
        pa += w0 * (ls * sh0); \
        pb += w1 * (lv0 * sx + lv1 * sy + lv2 * sz); \
        const float t2 = w2 * ls; \
        p30 += t2 * sx; p31 += t2 * sy; p32 += t2 * sz; \
        const float t3 = w3 * sh0; \
        p40 += t3 * lv0; p41 += t3 * lv1; p42 += t3 * lv2; \
        p50 += w4 * (lv1 * sz - lv2 * sy); \
        p51 += w4 * (lv2 * sx - lv0 * sz); \
        p52 += w4 * (lv0 * sy - lv1 * sx); \
    } while (0)

#define PREFETCH(ptr) \
        const float4 q0 = ((const float4*)(ptr))[0]; \
        const float4 q1 = ((const float4*)(ptr))[1]; \
        const float4 q2 = ((const float4*)(ptr))[2]; \
        const float  qh7 = (ptr)[12]; \
        const float4 nxv = *(const float4*)(x + (size_t)__float_as_int(q0.x) * 128 + 4 * u)

#define ROTATE() do { r0 = q0; r1 = q1; r2 = q2; h7 = qh7; xv = nxv; } while (0)

    if (cnt > 0) {
        const int np = cnt >> 1;                       // full pairs
        const float* rl = epack + (size_t)(end - 1) * 16;  // last record
        const float* r  = epack + ((size_t)beg + half) * 16;
        if (r > rl) r = rl;                            // only when cnt==1, half==1
        float4 r0 = ((const float4*)r)[0];
        float4 r1 = ((const float4*)r)[1];
        float4 r2 = ((const float4*)r)[2];
        float  h7 = r[12];
        float4 xv = *(const float4*)(x + (size_t)__float_as_int(r0.x) * 128 + 4 * u);

        // steady state: prefetch r+2 records, provably < end
        for (int it = 0; it < np - 1; ++it) {
            r += 32;
            PREFETCH(r);
            EDGE_BODY();
            ROTATE();
        }

        if (np > 0) {
            if (cnt & 1) {
                // last full pair, prefetching the (uniform) tail record
                {
                    PREFETCH(rl);
                    EDGE_BODY();
                    ROTATE();
                }
                // tail edge: half 0 real, half 1 zeroed via sh mask
                const float mask = (half == 0) ? 1.f : 0.f;
                r0.y *= mask; r0.z *= mask; r0.w *= mask; r1.x *= mask;
                EDGE_BODY();
            } else {
                EDGE_BODY();
            }
        } else {
            // cnt == 1: both halves hold record end-1; mask half 1
            const float mask = (half == 0) ? 1.f : 0.f;
            r0.y *= mask; r0.z *= mask; r0.w *= mask; r1.x *= mask;
            EDGE_BODY();
        }
    }
#undef EDGE_BODY
#undef PREFETCH
#undef ROTATE

    // combine even/odd-edge partials across halves
    pa  += __shfl_xor(pa, 32);  pb  += __shfl_xor(pb, 32);
    p30 += __shfl_xor(p30, 32); p31 += __shfl_xor(p31, 32); p32 += __shfl_xor(p32, 32);
    p40 += __shfl_xor(p40, 32); p41 += __shfl_xor(p41, 32); p42 += __shfl_xor(p42, 32);
    p50 += __shfl_xor(p50, 32); p51 += __shfl_xor(p51, 32); p52 += __shfl_xor(p52, 32);

    // msg layout: [0..31]=p1, [32..63]=p2, vectors c-major: [64 + c*96 + uu],
    // uu = (path-3)*32 + u
    {
        float* mg = msg[w];
        if (half == 0) {
            mg[u]              = pa  * INV_NEIGH;
            mg[32 + u]         = pb  * (INV3C * INV_NEIGH);
            mg[64 + u]         = p30 * INV_NEIGH;
            mg[64 + 96 + u]    = p31 * INV_NEIGH;
            mg[64 + 192 + u]   = p32 * INV_NEIGH;
        } else {
            mg[64 + 32 + u]        = p40 * INV_NEIGH;
            mg[64 + 96 + 32 + u]   = p41 * INV_NEIGH;
            mg[64 + 192 + 32 + u]  = p42 * INV_NEIGH;
            const float f = INV2C * INV_NEIGH;
            mg[64 + 64 + u]        = p50 * f;
            mg[64 + 96 + 64 + u]   = p51 * f;
            mg[64 + 192 + 64 + u]  = p52 * f;
        }
    }
    __syncthreads();

    // divergence-free cooperative fold of linear_2 for the block's 4 nodes;
    // W2 read directly from global (L1-resident: 20KB, coalesced, repeating)
    {
        const int nb = blockIdx.x * 4;
        const int t = threadIdx.x;
        if (t < 128) {
            const int node = t >> 5, o = t & 31;
            float s = 0.f;
#pragma unroll
            for (int uu = 0; uu < 64; ++uu) s += msg[node][uu] * W2_s[uu * 32 + o];
            out[(size_t)(nb + node) * 128 + o] += s * INV_SQRT_2MUL;
        } else {
            const int node = (t - 128) >> 5, vch = t & 31;
            float s0 = 0.f, s1 = 0.f, s2 = 0.f;
#pragma unroll
            for (int uu = 0; uu < 96; ++uu) {
                const float wgt = W2_v[uu * 32 + vch];
                s0 += msg[node][64 + uu]       * wgt;
                s1 += msg[node][64 + 96 + uu]  * wgt;
                s2 += msg[node][64 + 192 + uu] * wgt;
            }
            float* po = out + (size_t)(nb + node) * 128 + 32 + vch * 3;
            po[0] += s0 * INV_SQRT_3MUL;
            po[1] += s1 * INV_SQRT_3MUL;
            po[2] += s2 * INV_SQRT_3MUL;
        }
    }
}

// ---------------------------------------------------------------------------
extern "C" void kernel_launch(void* const* d_in, const int* in_sizes, int n_in,
                              void* d_out, int out_size, void* d_ws, size_t ws_size,
                              hipStream_t stream) {
    const float* node_s   = (const float*)d_in[0];
    const float* node_v   = (const float*)d_in[1];
    const float* attrs    = (const float*)d_in[2];
    const float* edge_emb = (const float*)d_in[3];
    const float* edge_sh0 = (const float*)d_in[4];
    const float* edge_sh1 = (const float*)d_in[5];
    const float* W1_s     = (const float*)d_in[6];
    const float* W1_v     = (const float*)d_in[7];
    const float* Wm1      = (const float*)d_in[8];
    const float* Wm2      = (const float*)d_in[9];
    const float* W2_s     = (const float*)d_in[10];
    const float* W2_v     = (const float*)d_in[11];
    const float* Wsc_s    = (const float*)d_in[12];
    const float* Wsc_v    = (const float*)d_in[13];
    const int*   edge_src = (const int*)d_in[14];
    const int*   edge_dst = (const int*)d_in[15];
    float* out = (float*)d_out;

    // workspace layout (unchanged)
    float* x     = (float*)d_ws;                     // N*128
    float* epack = x + (size_t)NN * 128;             // E*16
    int*   counts  = (int*)(epack + (size_t)NE * 16);// N
    int*   offsets = counts + NN;                    // N+1
    int*   cursor  = offsets + NN + 1;               // N
    int*   escan   = cursor + NN;                    // N
    int*   bsum    = escan + NN;                     // SCANB

    hipMemsetAsync(counts, 0, NN * sizeof(int), stream);

    k_node<<<NN / NPB, 256, 0, stream>>>(node_s, node_v, attrs,
                                         W1_s, W1_v, Wsc_s, Wsc_v,
                                         edge_dst, counts, x, out);
    k_scan_a<<<SCANB, 1024, 0, stream>>>(counts, escan, bsum);
    k_scan_c<<<SCANB, 1024, 0, stream>>>(escan, bsum, offsets, cursor);
    k_pack<<<(NE + 255) / 256, 256, 0, stream>>>(edge_emb, edge_sh0, edge_sh1,
                                                 edge_src, edge_dst, Wm1,
                                                 cursor, epack);
    k_gather<<<NN / 4, 256, 0, stream>>>(x, epack, Wm2, W2_s, W2_v,
                                         offsets, out);
}

// Round 6
// 403.873 us; speedup vs baseline: 1.2333x; 1.0071x over previous
//
#include <hip/hip_runtime.h>
#include <math.h>

#define NN 50000
#define NE 800000
#define MUL 32
#define NPB 4       /* nodes per k_node block */
#define SCANB 49    /* ceil(NN/1024) */

static __device__ __forceinline__ float sigmoidf_(float v) {
    return 1.0f / (1.0f + __expf(-v));
}

#define INV_SQRT_MUL   0.17677669529663687f   /* 1/sqrt(32) */
#define INV_SQRT_NEMB  0.35355339059327373f   /* 1/sqrt(8)  */
#define INV_SQRT_HID   0.35355339059327373f   /* 1/sqrt(8)  */
#define INV3C          0.5773502691896258f    /* 1/sqrt(3)  */
#define INV2C          0.7071067811865476f    /* 1/sqrt(2)  */
#define INV_NEIGH      0.25f                  /* 1/sqrt(16) */
#define INV_SQRT_2MUL  0.125f                 /* 1/sqrt(64) */
#define INV_SQRT_3MUL  0.10206207261596575f   /* 1/sqrt(96) */
#define NSC            0.0625f                /* 1/sqrt(32*8) */

// ---------------------------------------------------------------------------
// K1 (unchanged): NPB=4 nodes/block, Wsc loaded once per block, fused dst
// histogram. x layout packed-per-u:
//   x[n*128 + 4*u + 0] = s[u],  x[n*128 + 4*u + 1 + c] = v[u][c]
// ---------------------------------------------------------------------------
__global__ __launch_bounds__(256) void k_node(
    const float* __restrict__ node_s, const float* __restrict__ node_v,
    const float* __restrict__ attrs,
    const float* __restrict__ W1_s, const float* __restrict__ W1_v,
    const float* __restrict__ Wsc_s, const float* __restrict__ Wsc_v,
    const int* __restrict__ edge_dst, int* __restrict__ counts,
    float* __restrict__ x, float* __restrict__ out)
{
    __shared__ float nd[NPB][136];
    __shared__ float gs[NPB][1024];
    __shared__ float gv[NPB][1024];
    const int t  = threadIdx.x;
    const int nb = blockIdx.x * NPB;

    {
        int g = blockIdx.x * 256 + t;
        if (g < NE) atomicAdd(&counts[edge_dst[g]], 1);
    }

#pragma unroll
    for (int i = t; i < NPB * 128; i += 256) {
        int nn = i >> 7, j = i & 127;
        nd[nn][j] = (j < 32) ? node_s[(nb + nn) * 32 + j]
                             : node_v[(nb + nn) * 96 + (j - 32)];
    }
    if (t < NPB * 8) nd[t >> 3][128 + (t & 7)] = attrs[(nb + (t >> 3)) * 8 + (t & 7)];
    __syncthreads();

    float at[NPB][8];
#pragma unroll
    for (int nn = 0; nn < NPB; ++nn)
#pragma unroll
        for (int a = 0; a < 8; ++a) at[nn][a] = nd[nn][128 + a];

#pragma unroll
    for (int r = 0; r < 4; ++r) {
        const int idx = t + 256 * r;
        const int u = idx >> 5, vch = idx & 31;
        float as[NPB] = {0.f, 0.f, 0.f, 0.f};
        float av[NPB] = {0.f, 0.f, 0.f, 0.f};
#pragma unroll
        for (int a = 0; a < 8; ++a) {
            const float ws = Wsc_s[(u * 8 + a) * 32 + vch];
            const float wvw = Wsc_v[(u * 8 + a) * 32 + vch];
#pragma unroll
            for (int nn = 0; nn < NPB; ++nn) {
                as[nn] += at[nn][a] * ws;
                av[nn] += at[nn][a] * wvw;
            }
        }
#pragma unroll
        for (int nn = 0; nn < NPB; ++nn) {
            gs[nn][idx] = as[nn];
            gv[nn][idx] = av[nn];
        }
    }
    __syncthreads();

    const int o  = t & 127;
    const int nh = t >> 7;
    if (o < 32) {
        float ax[2] = {0.f, 0.f}, asc[2] = {0.f, 0.f};
#pragma unroll
        for (int uu = 0; uu < 32; ++uu) {
            const float w1 = W1_s[uu * 32 + o];
#pragma unroll
            for (int r2 = 0; r2 < 2; ++r2) {
                const int nn = nh + 2 * r2;
                const float s = nd[nn][uu];
                ax[r2]  += s * w1;
                asc[r2] += s * gs[nn][(uu << 5) + o];
            }
        }
#pragma unroll
        for (int r2 = 0; r2 < 2; ++r2) {
            const int nidx = nb + nh + 2 * r2;
            x[(size_t)nidx * 128 + 4 * o] = ax[r2] * INV_SQRT_MUL;
            out[(size_t)nidx * 128 + o]   = asc[r2] * NSC;
        }
    } else {
        const int q = o - 32;
        const int vch = q / 3, c = q - 3 * vch;
        float ax[2] = {0.f, 0.f}, asc[2] = {0.f, 0.f};
#pragma unroll
        for (int uu = 0; uu < 32; ++uu) {
            const float w1 = W1_v[uu * 32 + vch];
#pragma unroll
            for (int r2 = 0; r2 < 2; ++r2) {
                const int nn = nh + 2 * r2;
                const float vv = nd[nn][32 + 3 * uu + c];
                ax[r2]  += vv * w1;
                asc[r2] += vv * gv[nn][(uu << 5) + vch];
            }
        }
#pragma unroll
        for (int r2 = 0; r2 < 2; ++r2) {
            const int nidx = nb + nh + 2 * r2;
            x[(size_t)nidx * 128 + 4 * vch + 1 + c] = ax[r2] * INV_SQRT_MUL;
            out[(size_t)nidx * 128 + o]             = asc[r2] * NSC;
        }
    }
}

// ---------------------------------------------------------------------------
// K3a: per-block exclusive scan (1024 elems/block) + block sums
// ---------------------------------------------------------------------------
__global__ __launch_bounds__(1024) void k_scan_a(
    const int* __restrict__ counts, int* __restrict__ escan,
    int* __restrict__ bsum)
{
    __shared__ int sh[1024];
    const int t = threadIdx.x;
    const int i = blockIdx.x * 1024 + t;
    int v = (i < NN) ? counts[i] : 0;
    sh[t] = v;
    __syncthreads();
    for (int off = 1; off < 1024; off <<= 1) {
        int u = (t >= off) ? sh[t - off] : 0;
        __syncthreads();
        sh[t] += u;
        __syncthreads();
    }
    if (i < NN) escan[i] = sh[t] - v;
    if (t == 1023) bsum[blockIdx.x] = sh[1023];
}

// ---------------------------------------------------------------------------
// K3c: per-block bsum prefix + add-back -> offsets[N+1], cursor[N]
// ---------------------------------------------------------------------------
__global__ __launch_bounds__(1024) void k_scan_c(
    const int* __restrict__ escan, const int* __restrict__ bsum,
    int* __restrict__ offsets, int* __restrict__ cursor)
{
    __shared__ int sbase;
    const int t = threadIdx.x;
    if (t < 64) {
        int v = (t < blockIdx.x) ? bsum[t] : 0;
        for (int off = 32; off > 0; off >>= 1) v += __shfl_xor(v, off, 64);
        if (t == 0) sbase = v;
    }
    __syncthreads();
    const int i = blockIdx.x * 1024 + t;
    if (i == 0) offsets[NN] = NE;
    if (i < NN) {
        int o = sbase + escan[i];
        offsets[i] = o;
        cursor[i] = o;
    }
}

// ---------------------------------------------------------------------------
// K4: pack — radial-MLP hidden h + 64B record at CSR position.
// record: [0]=src(bits) [1]=sh0 [2..4]=sh1 [5..12]=h [13..15]=pad
// ---------------------------------------------------------------------------
__global__ __launch_bounds__(256) void k_pack(
    const float* __restrict__ edge_emb, const float* __restrict__ edge_sh0,
    const float* __restrict__ edge_sh1,
    const int* __restrict__ edge_src, const int* __restrict__ edge_dst,
    const float* __restrict__ Wm1,
    int* __restrict__ cursor, float* __restrict__ epack)
{
    int e = blockIdx.x * 256 + threadIdx.x;
    if (e >= NE) return;
    const float4* p = (const float4*)(edge_emb + e * 8);
    float4 a = p[0], b = p[1];
    float emb[8] = {a.x, a.y, a.z, a.w, b.x, b.y, b.z, b.w};
    float h[8];
#pragma unroll
    for (int j = 0; j < 8; ++j) {
        float s = 0.f;
#pragma unroll
        for (int k = 0; k < 8; ++k) s += emb[k] * Wm1[k * 8 + j];
        s *= INV_SQRT_NEMB;
        h[j] = s * sigmoidf_(s);
    }
    float sh0 = edge_sh0[e];
    float sx = edge_sh1[3 * e], sy = edge_sh1[3 * e + 1], sz = edge_sh1[3 * e + 2];
    int src = edge_src[e];
    int pos = atomicAdd(&cursor[edge_dst[e]], 1);
    float4* op = (float4*)(epack + (size_t)pos * 16);
    op[0] = make_float4(__int_as_float(src), sh0, sx, sy);
    op[1] = make_float4(sz, h[0], h[1], h[2]);
    op[2] = make_float4(h[3], h[4], h[5], h[6]);
    op[3] = make_float4(h[7], 0.f, 0.f, 0.f);
}

// ---------------------------------------------------------------------------
// K5 (v9): identical structure to v8 but with __launch_bounds__(256, 4):
// min 4 waves/EU -> VGPR cap 128. v8's implicit 8-wave target squeezed the
// ~90-register live set (wc[5][8] + 11 accumulators + 2x record/xv pipeline)
// into 64 VGPRs -> spill/remat inside the edge loop (VALUBusy-implied inst
// count was ~2.5x the algorithmic need). Trade phantom occupancy (measured
// 39% either way) for a clean register allocation.
// ---------------------------------------------------------------------------
__global__ __launch_bounds__(256, 4) void k_gather(
    const float* __restrict__ x, const float* __restrict__ epack,
    const float* __restrict__ Wm2, const float* __restrict__ W2_s,
    const float* __restrict__ W2_v,
    const int* __restrict__ offsets, float* __restrict__ out)
{
    __shared__ float msg[4][360];               // per-wave message, padded

    const int w    = threadIdx.x >> 6;       // wave id = node within block
    const int L    = threadIdx.x & 63;
    const int u    = L & 31;
    const int half = L >> 5;
    const int n    = blockIdx.x * 4 + w;     // NN = 50000 = 12500*4, always valid

    // per-lane Wm2 columns for ALL 5 paths (role-independent), pre-scaled
    float wc[5][8];
#pragma unroll
    for (int p = 0; p < 5; ++p)
#pragma unroll
        for (int q = 0; q < 8; ++q)
            wc[p][q] = Wm2[q * 160 + p * 32 + u] * INV_SQRT_HID;

    float pa = 0.f, pb = 0.f;
    float p30 = 0.f, p31 = 0.f, p32 = 0.f;
    float p40 = 0.f, p41 = 0.f, p42 = 0.f;
    float p50 = 0.f, p51 = 0.f, p52 = 0.f;

    const int beg = offsets[n];
    const int end = offsets[n + 1];
    const int cnt = end - beg;

#define EDGE_BODY() do { \
        const float sh0 = r0.y, sx = r0.z, sy = r0.w, sz = r1.x; \
        const float w0 = r1.y*wc[0][0] + r1.z*wc[0][1] + r1.w*wc[0][2] + r2.x*wc[0][3] \
                       + r2.y*wc[0][4] + r2.z*wc[0][5] + r2.w*wc[0][6] + h7*wc[0][7]; \
        const float w1 = r1.y*wc[1][0] + r1.z*wc[1][1] + r1.w*wc[1][2] + r2.x*wc[1][3] \
                       + r2.y*wc[1][4] + r2.z*wc[1][5] + r2.w*wc[1][6] + h7*wc[1][7]; \
        const float w2 = r1.y*wc[2][0] + r1.z*wc[2][1] + r1.w*wc[2][2] + r2.x*wc[2][3] \
                       + r2.y*wc[2][4] + r2.z*wc[2][5] + r2.w*wc[2][6] + h7*wc[2][7]; \
        const float w3 = r1.y*wc[3][0] + r1.z*wc[3][1] + r1.w*wc[3][2] + r2.x*wc[3][3] \
                       + r2.y*wc[3][4] + r2.z*wc[3][5] + r2.w*wc[3][6] + h7*wc[3][7]; \
        const float w4 = r1.y*wc[4][0] + r1.z*wc[4][1] + r1.w*wc[4][2] + r2.x*wc[4][3] \
                       + r2.y*wc[4][4] + r2.z*wc[4][5] + r2.w*wc[4][6] + h7*wc[4][7]; \
        const float ls = xv.x, lv0 = xv.y, lv1 = xv.z, lv2 = xv.w; \
        pa += w0 * (ls * sh0); \
        pb += w1 * (lv0 * sx + lv1 * sy + lv2 * sz); \
        const float t2 = w2 * ls; \
        p30 += t2 * sx; p31 += t2 * sy; p32 += t2 * sz; \
        const float t3 = w3 * sh0; \
        p40 += t3 * lv0; p41 += t3 * lv1; p42 += t3 * lv2; \
        p50 += w4 * (lv1 * sz - lv2 * sy); \
        p51 += w4 * (lv2 * sx - lv0 * sz); \
        p52 += w4 * (lv0 * sy - lv1 * sx); \
    } while (0)

#define PREFETCH(ptr) \
        const float4 q0 = ((const float4*)(ptr))[0]; \
        const float4 q1 = ((const float4*)(ptr))[1]; \
        const float4 q2 = ((const float4*)(ptr))[2]; \
        const float  qh7 = (ptr)[12]; \
        const float4 nxv = *(const float4*)(x + (size_t)__float_as_int(q0.x) * 128 + 4 * u)

#define ROTATE() do { r0 = q0; r1 = q1; r2 = q2; h7 = qh7; xv = nxv; } while (0)

    if (cnt > 0) {
        const int np = cnt >> 1;                       // full pairs
        const float* rl = epack + (size_t)(end - 1) * 16;  // last record
        const float* r  = epack + ((size_t)beg + half) * 16;
        if (r > rl) r = rl;                            // only when cnt==1, half==1
        float4 r0 = ((const float4*)r)[0];
        float4 r1 = ((const float4*)r)[1];
        float4 r2 = ((const float4*)r)[2];
        float  h7 = r[12];
        float4 xv = *(const float4*)(x + (size_t)__float_as_int(r0.x) * 128 + 4 * u);

        // steady state: prefetch r+2 records, provably < end
        for (int it = 0; it < np - 1; ++it) {
            r += 32;
            PREFETCH(r);
            EDGE_BODY();
            ROTATE();
        }

        if (np > 0) {
            if (cnt & 1) {
                // last full pair, prefetching the (uniform) tail record
                {
                    PREFETCH(rl);
                    EDGE_BODY();
                    ROTATE();
                }
                // tail edge: half 0 real, half 1 zeroed via sh mask
                const float mask = (half == 0) ? 1.f : 0.f;
                r0.y *= mask; r0.z *= mask; r0.w *= mask; r1.x *= mask;
                EDGE_BODY();
            } else {
                EDGE_BODY();
            }
        } else {
            // cnt == 1: both halves hold record end-1; mask half 1
            const float mask = (half == 0) ? 1.f : 0.f;
            r0.y *= mask; r0.z *= mask; r0.w *= mask; r1.x *= mask;
            EDGE_BODY();
        }
    }
#undef EDGE_BODY
#undef PREFETCH
#undef ROTATE

    // combine even/odd-edge partials across halves
    pa  += __shfl_xor(pa, 32);  pb  += __shfl_xor(pb, 32);
    p30 += __shfl_xor(p30, 32); p31 += __shfl_xor(p31, 32); p32 += __shfl_xor(p32, 32);
    p40 += __shfl_xor(p40, 32); p41 += __shfl_xor(p41, 32); p42 += __shfl_xor(p42, 32);
    p50 += __shfl_xor(p50, 32); p51 += __shfl_xor(p51, 32); p52 += __shfl_xor(p52, 32);

    // msg layout: [0..31]=p1, [32..63]=p2, vectors c-major: [64 + c*96 + uu],
    // uu = (path-3)*32 + u
    {
        float* mg = msg[w];
        if (half == 0) {
            mg[u]              = pa  * INV_NEIGH;
            mg[32 + u]         = pb  * (INV3C * INV_NEIGH);
            mg[64 + u]         = p30 * INV_NEIGH;
            mg[64 + 96 + u]    = p31 * INV_NEIGH;
            mg[64 + 192 + u]   = p32 * INV_NEIGH;
        } else {
            mg[64 + 32 + u]        = p40 * INV_NEIGH;
            mg[64 + 96 + 32 + u]   = p41 * INV_NEIGH;
            mg[64 + 192 + 32 + u]  = p42 * INV_NEIGH;
            const float f = INV2C * INV_NEIGH;
            mg[64 + 64 + u]        = p50 * f;
            mg[64 + 96 + 64 + u]   = p51 * f;
            mg[64 + 192 + 64 + u]  = p52 * f;
        }
    }
    __syncthreads();

    // divergence-free cooperative fold of linear_2 for the block's 4 nodes;
    // W2 read directly from global (L1-resident: 20KB, coalesced, repeating)
    {
        const int nb = blockIdx.x * 4;
        const int t = threadIdx.x;
        if (t < 128) {
            const int node = t >> 5, o = t & 31;
            float s = 0.f;
#pragma unroll
            for (int uu = 0; uu < 64; ++uu) s += msg[node][uu] * W2_s[uu * 32 + o];
            out[(size_t)(nb + node) * 128 + o] += s * INV_SQRT_2MUL;
        } else {
            const int node = (t - 128) >> 5, vch = t & 31;
            float s0 = 0.f, s1 = 0.f, s2 = 0.f;
#pragma unroll
            for (int uu = 0; uu < 96; ++uu) {
                const float wgt = W2_v[uu * 32 + vch];
                s0 += msg[node][64 + uu]       * wgt;
                s1 += msg[node][64 + 96 + uu]  * wgt;
                s2 += msg[node][64 + 192 + uu] * wgt;
            }
            float* po = out + (size_t)(nb + node) * 128 + 32 + vch * 3;
            po[0] += s0 * INV_SQRT_3MUL;
            po[1] += s1 * INV_SQRT_3MUL;
            po[2] += s2 * INV_SQRT_3MUL;
        }
    }
}

// ---------------------------------------------------------------------------
extern "C" void kernel_launch(void* const* d_in, const int* in_sizes, int n_in,
                              void* d_out, int out_size, void* d_ws, size_t ws_size,
                              hipStream_t stream) {
    const float* node_s   = (const float*)d_in[0];
    const float* node_v   = (const float*)d_in[1];
    const float* attrs    = (const float*)d_in[2];
    const float* edge_emb = (const float*)d_in[3];
    const float* edge_sh0 = (const float*)d_in[4];
    const float* edge_sh1 = (const float*)d_in[5];
    const float* W1_s     = (const float*)d_in[6];
    const float* W1_v     = (const float*)d_in[7];
    const float* Wm1      = (const float*)d_in[8];
    const float* Wm2      = (const float*)d_in[9];
    const float* W2_s     = (const float*)d_in[10];
    const float* W2_v     = (const float*)d_in[11];
    const float* Wsc_s    = (const float*)d_in[12];
    const float* Wsc_v    = (const float*)d_in[13];
    const int*   edge_src = (const int*)d_in[14];
    const int*   edge_dst = (const int*)d_in[15];
    float* out = (float*)d_out;

    // workspace layout (unchanged)
    float* x     = (float*)d_ws;                     // N*128
    float* epack = x + (size_t)NN * 128;             // E*16
    int*   counts  = (int*)(epack + (size_t)NE * 16);// N
    int*   offsets = counts + NN;                    // N+1
    int*   cursor  = offsets + NN + 1;               // N
    int*   escan   = cursor + NN;                    // N
    int*   bsum    = escan + NN;                     // SCANB

    hipMemsetAsync(counts, 0, NN * sizeof(int), stream);

    k_node<<<NN / NPB, 256, 0, stream>>>(node_s, node_v, attrs,
                                         W1_s, W1_v, Wsc_s, Wsc_v,
                                         edge_dst, counts, x, out);
    k_scan_a<<<SCANB, 1024, 0, stream>>>(counts, escan, bsum);
    k_scan_c<<<SCANB, 1024, 0, stream>>>(escan, bsum, offsets, cursor);
    k_pack<<<(NE + 255) / 256, 256, 0, stream>>>(edge_emb, edge_sh0, edge_sh1,
                                                 edge_src, edge_dst, Wm1,
                                                 cursor, epack);
    k_gather<<<NN / 4, 256, 0, stream>>>(x, epack, Wm2, W2_s, W2_v,
                                         offsets, out);
}